// Round 1
// baseline (226.122 us; speedup 1.0000x reference)
//
#include <hip/hip_runtime.h>
#include <math.h>

#define NPTS 8192
#define NRB 20
#define NAB 72
#define WS_STRIDE 96   // ints per slide: [0..19] rhist, [20..91] ahist, [92] ncoll

__device__ __forceinline__ const float* slide_ptr(const float* c0, const float* c1,
                                                  const float* c2, int s) {
  return s == 0 ? c0 : (s == 1 ? c1 : c2);
}

// One block per slide: center (double-acc), rmax, radial+angular histograms.
__global__ __launch_bounds__(256) void stats_kernel(const float* __restrict__ c0,
                                                    const float* __restrict__ c1,
                                                    const float* __restrict__ c2,
                                                    int* __restrict__ ws) {
  const int s = blockIdx.x;
  const float* coords = slide_ptr(c0, c1, c2, s);
  const int t = threadIdx.x;

  __shared__ double redd[256];
  __shared__ float  redf[256];
  __shared__ float  cxs, cys, rmaxps;
  __shared__ int    h[NRB + NAB];

  // pass 1: center = mean(coords) (double accumulation, rounded to f32 like jnp mean)
  double sx = 0.0, sy = 0.0;
  for (int i = t; i < NPTS; i += 256) {
    sx += (double)coords[2 * i];
    sy += (double)coords[2 * i + 1];
  }
  redd[t] = sx; __syncthreads();
  for (int o = 128; o > 0; o >>= 1) { if (t < o) redd[t] += redd[t + o]; __syncthreads(); }
  if (t == 0) cxs = (float)(redd[0] / (double)NPTS);
  __syncthreads();
  redd[t] = sy; __syncthreads();
  for (int o = 128; o > 0; o >>= 1) { if (t < o) redd[t] += redd[t + o]; __syncthreads(); }
  if (t == 0) cys = (float)(redd[0] / (double)NPTS);
  __syncthreads();
  const float cx = cxs, cy = cys;

  // pass 2: rmax (f32 chain matching jnp.linalg.norm: mul,mul,add,sqrt — no fma)
  float rm = 0.0f;
  for (int i = t; i < NPTS; i += 256) {
    float dx = __fsub_rn(coords[2 * i], cx);
    float dy = __fsub_rn(coords[2 * i + 1], cy);
    float r  = __fsqrt_rn(__fadd_rn(__fmul_rn(dx, dx), __fmul_rn(dy, dy)));
    rm = fmaxf(rm, r);
  }
  redf[t] = rm; __syncthreads();
  for (int o = 128; o > 0; o >>= 1) { if (t < o) redf[t] = fmaxf(redf[t], redf[t + o]); __syncthreads(); }
  if (t == 0) rmaxps = __fadd_rn(redf[0], 1e-8f);
  if (t < NRB + NAB) h[t] = 0;
  __syncthreads();
  const float rmaxp = rmaxps;

  // pass 3: histograms (exact f32 binning chains of the reference)
  for (int i = t; i < NPTS; i += 256) {
    float dx = __fsub_rn(coords[2 * i], cx);
    float dy = __fsub_rn(coords[2 * i + 1], cy);
    float r  = __fsqrt_rn(__fadd_rn(__fmul_rn(dx, dx), __fmul_rn(dy, dy)));
    float rn = __fdiv_rn(r, rmaxp);
    int ri = (int)floorf(__fmul_rn(rn, 20.0f));
    ri = min(max(ri, 0), NRB - 1);
    atomicAdd(&h[ri], 1);
    // angle: correctly-rounded f32 atan2 via double, then the reference's f32 chain
    float ang = (float)atan2((double)dy, (double)dx);
    float tt = __fadd_rn(ang, 3.14159274101257324f);            // + float(pi)
    float uu = __fdiv_rn(tt, 6.28318548202514648f);             // / float(2*pi)
    float vv = __fmul_rn(uu, 72.0f);
    int ai = (int)floorf(vv);
    ai = min(max(ai, 0), NAB - 1);
    atomicAdd(&h[NRB + ai], 1);
  }
  __syncthreads();
  int* o = ws + s * WS_STRIDE;
  if (t < NRB + NAB) o[t] = h[t];
  if (t == 0) o[NRB + NAB] = 0;   // zero collision counter for coll_kernel
}

// 384 blocks: 3 slides x 128 row-blocks. 64 rows/block, 4-way j-split.
// A wave's 64 lanes = 64 consecutive rows, same j => broadcast load (L1-friendly).
__global__ __launch_bounds__(256) void coll_kernel(const float* __restrict__ c0,
                                                   const float* __restrict__ c1,
                                                   const float* __restrict__ c2,
                                                   int* __restrict__ ws) {
  const int bi = blockIdx.x;
  const int s  = bi >> 7;        // 128 row-blocks per slide
  const int rb = bi & 127;
  const float2* coords = (const float2*)slide_ptr(c0, c1, c2, s);
  const int t = threadIdx.x;
  const int lane = t & 63;
  const int seg  = t >> 6;       // 0..3 quarter of the j range
  const int row  = rb * 64 + lane;
  const float2 p = coords[row];
  float d2min = INFINITY;
  const int j0 = seg * 2048;
  #pragma unroll 8
  for (int j = j0; j < j0 + 2048; ++j) {
    float2 q = coords[j];
    float dx = p.x - q.x;
    float dy = p.y - q.y;
    float d2 = dx * dx + dy * dy;
    d2 = (j == row) ? INFINITY : d2;   // exclude the diagonal
    d2min = fminf(d2min, d2);
  }
  __shared__ float dmin[256];
  dmin[t] = d2min;
  __syncthreads();
  if (t < 64) {
    float m = fminf(fminf(dmin[t], dmin[t + 64]), fminf(dmin[t + 128], dmin[t + 192]));
    unsigned long long b = __ballot(m < 1e-4f);   // d < 0.01  <=>  d^2 < 1e-4
    if (t == 0) atomicAdd(&ws[s * WS_STRIDE + NRB + NAB], (int)__popcll(b));
  }
}

// One block: 5-coefficient DFT magnitudes, assemble descs[3][26], variance.
__global__ __launch_bounds__(128) void final_kernel(const int* __restrict__ ws,
                                                    float* __restrict__ out) {
  __shared__ double fr[15][8], fi[15][8];
  __shared__ float descs[3][26];
  const int t = threadIdx.x;
  if (t < 120) {
    const int part = t & 7;
    const int sk = t >> 3;       // 0..14 = slide*5 + k
    const int s = sk / 5;
    const int k = sk % 5;
    const int* ah = ws + s * WS_STRIDE + NRB;
    const float meanv = __fdiv_rn(8192.0f, 72.0f);   // counts always sum to 8192
    double sr = 0.0, si = 0.0;
    for (int j = part; j < NAB; j += 8) {
      float a = __fsub_rn((float)ah[j], meanv);      // == reference's f32 ahist values
      double ang = -2.0 * M_PI * (double)(j * k) / 72.0;
      double sn, cs;
      sincos(ang, &sn, &cs);
      sr += (double)a * cs;
      si += (double)a * sn;
    }
    fr[sk][part] = sr; fi[sk][part] = si;
  }
  __syncthreads();
  if (t < 15) {
    double sr = 0.0, si = 0.0;
    for (int p = 0; p < 8; ++p) { sr += fr[t][p]; si += fi[t][p]; }
    descs[t / 5][20 + t % 5] = (float)sqrt(sr * sr + si * si);
  }
  if (t < 60) {
    descs[t / 20][t % 20] = __fdiv_rn((float)ws[(t / 20) * WS_STRIDE + (t % 20)], 8192.0f);
  }
  if (t >= 120 && t < 123) {
    int s = t - 120;
    descs[s][25] = __fdiv_rn((float)ws[s * WS_STRIDE + NRB + NAB], 8192.0f);
  }
  __syncthreads();
  if (t == 0) {
    double acc = 0.0;
    for (int j = 0; j < 26; ++j) {
      double a = descs[0][j], b = descs[1][j], c = descs[2][j];
      double m = (a + b + c) / 3.0;
      acc += ((a - m) * (a - m) + (b - m) * (b - m) + (c - m) * (c - m)) * 0.5;
    }
    out[0] = (float)(acc / 26.0);
  }
}

extern "C" void kernel_launch(void* const* d_in, const int* in_sizes, int n_in,
                              void* d_out, int out_size, void* d_ws, size_t ws_size,
                              hipStream_t stream) {
  const float* c0 = (const float*)d_in[0];
  const float* c1 = (const float*)d_in[1];
  const float* c2 = (const float*)d_in[2];
  int* ws = (int*)d_ws;
  float* out = (float*)d_out;
  hipLaunchKernelGGL(stats_kernel, dim3(3),   dim3(256), 0, stream, c0, c1, c2, ws);
  hipLaunchKernelGGL(coll_kernel,  dim3(384), dim3(256), 0, stream, c0, c1, c2, ws);
  hipLaunchKernelGGL(final_kernel, dim3(1),   dim3(128), 0, stream, ws, out);
}

// Round 2
// 80.276 us; speedup vs baseline: 2.8168x; 2.8168x over previous
//
#include <hip/hip_runtime.h>
#include <math.h>

#define NPTS 8192
#define NRB 20
#define NAB 72
#define WS_STRIDE 96       // ints per slide for histograms
#define DWS_OFF 1024       // uint offset in ws where per-row d2min lives (3*8192)

__device__ __forceinline__ const float* slide_ptr(const float* c0, const float* c1,
                                                  const float* c2, int s) {
  return s == 0 ? c0 : (s == 1 ? c1 : c2);
}

// One block per slide: center (double-acc), rmax, radial+angular histograms.
// Also initializes the per-row d2min array to +inf for coll_kernel.
__global__ __launch_bounds__(256) void stats_kernel(const float* __restrict__ c0,
                                                    const float* __restrict__ c1,
                                                    const float* __restrict__ c2,
                                                    int* __restrict__ ws) {
  const int s = blockIdx.x;
  const float* coords = slide_ptr(c0, c1, c2, s);
  const float4* c4 = (const float4*)coords;   // 2 points per float4
  const int t = threadIdx.x;

  // init d2min region for this slide
  unsigned* dws = (unsigned*)ws + DWS_OFF + s * NPTS;
  for (int i = t; i < NPTS; i += 256) dws[i] = 0x7F800000u;  // +inf

  __shared__ double redd[256];
  __shared__ float  redf[256];
  __shared__ float  cxs, cys, rmaxps;
  __shared__ int    h[NRB + NAB];

  // pass 1: center = mean (double accumulation, rounded to f32 like jnp mean)
  double sx = 0.0, sy = 0.0;
  for (int i = t; i < NPTS / 2; i += 256) {
    float4 v = c4[i];
    sx += (double)v.x + (double)v.z;
    sy += (double)v.y + (double)v.w;
  }
  redd[t] = sx; __syncthreads();
  for (int o = 128; o > 0; o >>= 1) { if (t < o) redd[t] += redd[t + o]; __syncthreads(); }
  if (t == 0) cxs = (float)(redd[0] / (double)NPTS);
  __syncthreads();
  redd[t] = sy; __syncthreads();
  for (int o = 128; o > 0; o >>= 1) { if (t < o) redd[t] += redd[t + o]; __syncthreads(); }
  if (t == 0) cys = (float)(redd[0] / (double)NPTS);
  __syncthreads();
  const float cx = cxs, cy = cys;

  // pass 2: rmax (f32 chain matching jnp.linalg.norm: mul,mul,add,sqrt — no fma)
  float rm = 0.0f;
  for (int i = t; i < NPTS / 2; i += 256) {
    float4 v = c4[i];
    float dx0 = __fsub_rn(v.x, cx), dy0 = __fsub_rn(v.y, cy);
    float dx1 = __fsub_rn(v.z, cx), dy1 = __fsub_rn(v.w, cy);
    float r0 = __fsqrt_rn(__fadd_rn(__fmul_rn(dx0, dx0), __fmul_rn(dy0, dy0)));
    float r1 = __fsqrt_rn(__fadd_rn(__fmul_rn(dx1, dx1), __fmul_rn(dy1, dy1)));
    rm = fmaxf(rm, fmaxf(r0, r1));
  }
  redf[t] = rm; __syncthreads();
  for (int o = 128; o > 0; o >>= 1) { if (t < o) redf[t] = fmaxf(redf[t], redf[t + o]); __syncthreads(); }
  if (t == 0) rmaxps = __fadd_rn(redf[0], 1e-8f);
  if (t < NRB + NAB) h[t] = 0;
  __syncthreads();
  const float rmaxp = rmaxps;

  // pass 3: histograms (exact f32 binning chains of the reference)
  for (int i = t; i < NPTS / 2; i += 256) {
    float4 v = c4[i];
    #pragma unroll
    for (int half = 0; half < 2; ++half) {
      float dx = __fsub_rn(half ? v.z : v.x, cx);
      float dy = __fsub_rn(half ? v.w : v.y, cy);
      float r  = __fsqrt_rn(__fadd_rn(__fmul_rn(dx, dx), __fmul_rn(dy, dy)));
      float rn = __fdiv_rn(r, rmaxp);
      int ri = (int)floorf(__fmul_rn(rn, 20.0f));
      ri = min(max(ri, 0), NRB - 1);
      atomicAdd(&h[ri], 1);
      float ang = (float)atan2((double)dy, (double)dx);
      float tt = __fadd_rn(ang, 3.14159274101257324f);           // + float(pi)
      float uu = __fdiv_rn(tt, 6.28318548202514648f);            // / float(2*pi)
      float vv = __fmul_rn(uu, 72.0f);
      int ai = (int)floorf(vv);
      ai = min(max(ai, 0), NAB - 1);
      atomicAdd(&h[NRB + ai], 1);
    }
  }
  __syncthreads();
  int* o = ws + s * WS_STRIDE;
  if (t < NRB + NAB) o[t] = h[t];
}

// n-body register-blocked min-distance.
// Grid: 3 slides x 4 row-blocks x 32 j-segments = 384 blocks.
// Each thread owns 8 rows (stride 256); block stages 256 j-points in LDS.
__global__ __launch_bounds__(256) void coll_kernel(const float* __restrict__ c0,
                                                   const float* __restrict__ c1,
                                                   const float* __restrict__ c2,
                                                   int* __restrict__ ws) {
  const int b   = blockIdx.x;
  const int s   = b >> 7;          // 128 blocks per slide
  const int rb  = (b >> 5) & 3;    // row-block (2048 rows)
  const int seg = b & 31;          // j-segment (256 points)
  const float2* coords = (const float2*)slide_ptr(c0, c1, c2, s);
  const int t  = threadIdx.x;
  const int j0 = seg * 256;
  const int r0 = rb * 2048;

  __shared__ float2 tile[256];
  tile[t] = coords[j0 + t];

  float px[8], py[8], dm[8];
  const int rbase = r0 + t;
  #pragma unroll
  for (int k = 0; k < 8; ++k) {
    float2 p = coords[rbase + k * 256];
    px[k] = p.x; py[k] = p.y; dm[k] = INFINITY;
  }
  __syncthreads();

  if ((seg >> 3) == rb) {
    // j-window overlaps this block's rows: exclude the diagonal per pair
    int diag[8];
    #pragma unroll
    for (int k = 0; k < 8; ++k) {
      int d = rbase + k * 256 - j0;
      diag[k] = (d >= 0 && d < 256) ? d : -1;
    }
    #pragma unroll 4
    for (int jj = 0; jj < 256; ++jj) {
      float2 q = tile[jj];
      #pragma unroll
      for (int k = 0; k < 8; ++k) {
        float dx = px[k] - q.x;
        float dy = py[k] - q.y;
        float d2 = fmaf(dy, dy, dx * dx);
        d2 = (jj == diag[k]) ? INFINITY : d2;
        dm[k] = fminf(dm[k], d2);
      }
    }
  } else {
    #pragma unroll 4
    for (int jj = 0; jj < 256; ++jj) {
      float2 q = tile[jj];
      #pragma unroll
      for (int k = 0; k < 8; ++k) {
        float dx = px[k] - q.x;
        float dy = py[k] - q.y;
        dm[k] = fminf(dm[k], fmaf(dy, dy, dx * dx));
      }
    }
  }

  // combine across j-segments: uint atomicMin == float min for nonneg floats
  unsigned* dws = (unsigned*)ws + DWS_OFF + s * NPTS;
  #pragma unroll
  for (int k = 0; k < 8; ++k)
    atomicMin(&dws[rbase + k * 256], __float_as_uint(dm[k]));
}

// One block: collision counts, 5-coefficient DFT magnitudes, descs, variance.
__global__ __launch_bounds__(256) void final_kernel(const int* __restrict__ ws,
                                                    float* __restrict__ out) {
  __shared__ double fr[15][8], fi[15][8];
  __shared__ float descs[3][26];
  __shared__ int redi[256];
  const int t = threadIdx.x;

  // collision counts: d2min < 1e-4  <=>  d < 0.01
  for (int s = 0; s < 3; ++s) {
    const unsigned* dws = (const unsigned*)ws + DWS_OFF + s * NPTS;
    int c = 0;
    for (int i = t; i < NPTS; i += 256)
      c += (__uint_as_float(dws[i]) < 1e-4f) ? 1 : 0;
    redi[t] = c; __syncthreads();
    for (int o = 128; o > 0; o >>= 1) { if (t < o) redi[t] += redi[t + o]; __syncthreads(); }
    if (t == 0) descs[s][25] = __fdiv_rn((float)redi[0], 8192.0f);
    __syncthreads();
  }

  if (t < 120) {
    const int part = t & 7;
    const int sk = t >> 3;       // 0..14 = slide*5 + k
    const int s = sk / 5;
    const int k = sk % 5;
    const int* ah = ws + s * WS_STRIDE + NRB;
    const float meanv = __fdiv_rn(8192.0f, 72.0f);   // counts always sum to 8192
    double sr = 0.0, si = 0.0;
    for (int j = part; j < NAB; j += 8) {
      float a = __fsub_rn((float)ah[j], meanv);      // == reference's f32 ahist values
      double ang = -2.0 * M_PI * (double)(j * k) / 72.0;
      double sn, cs;
      sincos(ang, &sn, &cs);
      sr += (double)a * cs;
      si += (double)a * sn;
    }
    fr[sk][part] = sr; fi[sk][part] = si;
  }
  __syncthreads();
  if (t < 15) {
    double sr = 0.0, si = 0.0;
    for (int p = 0; p < 8; ++p) { sr += fr[t][p]; si += fi[t][p]; }
    descs[t / 5][20 + t % 5] = (float)sqrt(sr * sr + si * si);
  }
  if (t < 60) {
    descs[t / 20][t % 20] = __fdiv_rn((float)ws[(t / 20) * WS_STRIDE + (t % 20)], 8192.0f);
  }
  __syncthreads();
  if (t == 0) {
    double acc = 0.0;
    for (int j = 0; j < 26; ++j) {
      double a = descs[0][j], b = descs[1][j], c = descs[2][j];
      double m = (a + b + c) / 3.0;
      acc += ((a - m) * (a - m) + (b - m) * (b - m) + (c - m) * (c - m)) * 0.5;
    }
    out[0] = (float)(acc / 26.0);
  }
}

extern "C" void kernel_launch(void* const* d_in, const int* in_sizes, int n_in,
                              void* d_out, int out_size, void* d_ws, size_t ws_size,
                              hipStream_t stream) {
  const float* c0 = (const float*)d_in[0];
  const float* c1 = (const float*)d_in[1];
  const float* c2 = (const float*)d_in[2];
  int* ws = (int*)d_ws;
  float* out = (float*)d_out;
  hipLaunchKernelGGL(stats_kernel, dim3(3),   dim3(256), 0, stream, c0, c1, c2, ws);
  hipLaunchKernelGGL(coll_kernel,  dim3(384), dim3(256), 0, stream, c0, c1, c2, ws);
  hipLaunchKernelGGL(final_kernel, dim3(1),   dim3(256), 0, stream, ws, out);
}

// Round 3
// 56.674 us; speedup vs baseline: 3.9899x; 1.4164x over previous
//
#include <hip/hip_runtime.h>
#include <math.h>

#define NPTS 8192
#define NRB 20
#define NAB 72
#define WS_STRIDE 96        // ints per slide for histograms
#define DBL_BYTE_OFF 2048   // byte offset of double partial-sum area (96 doubles)
#define DWS_OFF 1024        // int offset of per-row d2min area (3*8192 uints)

__device__ __forceinline__ const float* slide_ptr(const float* c0, const float* c1,
                                                  const float* c2, int s) {
  return s == 0 ? c0 : (s == 1 ? c1 : c2);
}

// 48 blocks = 3 slides x 16 parts. Partial double sums (512 pts each),
// init d2min to +inf, zero histogram area.
__global__ __launch_bounds__(256) void prep_kernel(const float* __restrict__ c0,
                                                   const float* __restrict__ c1,
                                                   const float* __restrict__ c2,
                                                   int* __restrict__ ws) {
  const int b = blockIdx.x;
  const int s = b >> 4, part = b & 15;
  const int t = threadIdx.x;
  const float4* c4 = (const float4*)slide_ptr(c0, c1, c2, s);
  float4 v = c4[part * 256 + t];          // 2 points per thread
  __shared__ double red[256];
  red[t] = (double)v.x + (double)v.z; __syncthreads();
  for (int o = 128; o > 0; o >>= 1) { if (t < o) red[t] += red[t + o]; __syncthreads(); }
  double* dbl = (double*)((char*)ws + DBL_BYTE_OFF);
  if (t == 0) dbl[s * 32 + part * 2] = red[0];
  __syncthreads();
  red[t] = (double)v.y + (double)v.w; __syncthreads();
  for (int o = 128; o > 0; o >>= 1) { if (t < o) red[t] += red[t + o]; __syncthreads(); }
  if (t == 0) dbl[s * 32 + part * 2 + 1] = red[0];

  unsigned* dws = (unsigned*)ws + DWS_OFF;
  dws[b * 512 + t]       = 0x7F800000u;   // +inf
  dws[b * 512 + 256 + t] = 0x7F800000u;
  if (t < 6) ws[b * 6 + t] = 0;           // 48*6 = 288 hist ints
}

// 816 blocks: 0..47 = histogram blocks (3 slides x 16 parts),
// 48..815 = pair-sweep blocks (3 slides x 4 row-blocks x 64 j-segments).
__global__ __launch_bounds__(256) void work_kernel(const float* __restrict__ c0,
                                                   const float* __restrict__ c1,
                                                   const float* __restrict__ c2,
                                                   int* __restrict__ ws) {
  const int b = blockIdx.x;
  const int t = threadIdx.x;

  if (b < 48) {
    // ---- histogram path ----
    const int s = b >> 4, part = b & 15;
    const float4* c4 = (const float4*)slide_ptr(c0, c1, c2, s);
    __shared__ int h[92];
    __shared__ float redf[256];
    __shared__ float rmaxs;
    for (int i = t; i < 92; i += 256) h[i] = 0;

    // center from fixed-order reduction of the 16 double partials
    const double* dbl = (const double*)((const char*)ws + DBL_BYTE_OFF);
    double sx = 0.0, sy = 0.0;
    for (int p = 0; p < 16; ++p) { sx += dbl[s * 32 + p * 2]; sy += dbl[s * 32 + p * 2 + 1]; }
    const float cx = (float)(sx / (double)NPTS);
    const float cy = (float)(sy / (double)NPTS);

    // rmax over the full slide (max is order-independent => deterministic)
    float rm = 0.0f;
    for (int i = 0; i < 16; ++i) {
      float4 v = c4[t + i * 256];
      float dx0 = __fsub_rn(v.x, cx), dy0 = __fsub_rn(v.y, cy);
      float dx1 = __fsub_rn(v.z, cx), dy1 = __fsub_rn(v.w, cy);
      float r0 = __fsqrt_rn(__fadd_rn(__fmul_rn(dx0, dx0), __fmul_rn(dy0, dy0)));
      float r1 = __fsqrt_rn(__fadd_rn(__fmul_rn(dx1, dx1), __fmul_rn(dy1, dy1)));
      rm = fmaxf(rm, fmaxf(r0, r1));
    }
    redf[t] = rm; __syncthreads();
    for (int o = 128; o > 0; o >>= 1) { if (t < o) redf[t] = fmaxf(redf[t], redf[t + o]); __syncthreads(); }
    if (t == 0) rmaxs = __fadd_rn(redf[0], 1e-8f);
    __syncthreads();
    const float rmaxp = rmaxs;

    // this block's 512 points: exact f32 binning chains of the reference
    float4 v = c4[part * 256 + t];
    #pragma unroll
    for (int half = 0; half < 2; ++half) {
      float dx = __fsub_rn(half ? v.z : v.x, cx);
      float dy = __fsub_rn(half ? v.w : v.y, cy);
      float r  = __fsqrt_rn(__fadd_rn(__fmul_rn(dx, dx), __fmul_rn(dy, dy)));
      float rn = __fdiv_rn(r, rmaxp);
      int ri = (int)floorf(__fmul_rn(rn, 20.0f));
      ri = min(max(ri, 0), NRB - 1);
      atomicAdd(&h[ri], 1);
      float ang = (float)atan2((double)dy, (double)dx);
      float tt = __fadd_rn(ang, 3.14159274101257324f);           // + float(pi)
      float uu = __fdiv_rn(tt, 6.28318548202514648f);            // / float(2*pi)
      float vv = __fmul_rn(uu, 72.0f);
      int ai = (int)floorf(vv);
      ai = min(max(ai, 0), NAB - 1);
      atomicAdd(&h[NRB + ai], 1);
    }
    __syncthreads();
    if (t < 92) atomicAdd(&ws[s * WS_STRIDE + t], h[t]);
    return;
  }

  // ---- pair-sweep path ----
  const int b2  = b - 48;
  const int s   = b2 >> 8;          // 256 blocks per slide
  const int rb  = (b2 >> 6) & 3;    // row-block (2048 rows)
  const int seg = b2 & 63;          // j-segment (128 points)
  const float2* coords = (const float2*)slide_ptr(c0, c1, c2, s);
  const float4* c4 = (const float4*)coords;
  const int j0 = seg * 128;
  const int r0 = rb * 2048;

  __shared__ float4 tile4[64];      // 128 points
  if (t < 64) tile4[t] = c4[seg * 64 + t];

  float px[8], py[8], dm[8];
  const int rbase = r0 + t;
  #pragma unroll
  for (int k = 0; k < 8; ++k) {
    float2 p = coords[rbase + k * 256];
    px[k] = p.x; py[k] = p.y; dm[k] = INFINITY;
  }
  __syncthreads();

  if ((seg >> 4) == rb) {
    int diag[8];
    #pragma unroll
    for (int k = 0; k < 8; ++k) {
      int d = rbase + k * 256 - j0;
      diag[k] = ((unsigned)d < 128u) ? d : -1;
    }
    #pragma unroll 4
    for (int u = 0; u < 64; ++u) {
      float4 q = tile4[u];
      #pragma unroll
      for (int k = 0; k < 8; ++k) {
        float dx0 = px[k] - q.x, dy0 = py[k] - q.y;
        float dx1 = px[k] - q.z, dy1 = py[k] - q.w;
        float d20 = fmaf(dy0, dy0, dx0 * dx0);
        float d21 = fmaf(dy1, dy1, dx1 * dx1);
        d20 = (diag[k] == 2 * u)     ? INFINITY : d20;
        d21 = (diag[k] == 2 * u + 1) ? INFINITY : d21;
        dm[k] = fminf(dm[k], fminf(d20, d21));
      }
    }
  } else {
    #pragma unroll 8
    for (int u = 0; u < 64; ++u) {
      float4 q = tile4[u];
      #pragma unroll
      for (int k = 0; k < 8; ++k) {
        float dx0 = px[k] - q.x, dy0 = py[k] - q.y;
        float dx1 = px[k] - q.z, dy1 = py[k] - q.w;
        float d20 = fmaf(dy0, dy0, dx0 * dx0);
        float d21 = fmaf(dy1, dy1, dx1 * dx1);
        dm[k] = fminf(dm[k], fminf(d20, d21));
      }
    }
  }

  unsigned* dws = (unsigned*)ws + DWS_OFF + s * NPTS;
  #pragma unroll
  for (int k = 0; k < 8; ++k)
    atomicMin(&dws[rbase + k * 256], __float_as_uint(dm[k]));
}

// One block: collision counts, 5-coefficient DFT magnitudes, descs, variance.
__global__ __launch_bounds__(256) void final_kernel(const int* __restrict__ ws,
                                                    float* __restrict__ out) {
  __shared__ double fr[15][8], fi[15][8];
  __shared__ float descs[3][26];
  __shared__ int redi[256];
  const int t = threadIdx.x;

  for (int s = 0; s < 3; ++s) {
    const unsigned* dws = (const unsigned*)ws + DWS_OFF + s * NPTS;
    int c = 0;
    for (int i = t; i < NPTS; i += 256)
      c += (__uint_as_float(dws[i]) < 1e-4f) ? 1 : 0;   // d<0.01 <=> d2<1e-4
    redi[t] = c; __syncthreads();
    for (int o = 128; o > 0; o >>= 1) { if (t < o) redi[t] += redi[t + o]; __syncthreads(); }
    if (t == 0) descs[s][25] = __fdiv_rn((float)redi[0], 8192.0f);
    __syncthreads();
  }

  if (t < 120) {
    const int part = t & 7;
    const int sk = t >> 3;
    const int s = sk / 5;
    const int k = sk % 5;
    const int* ah = ws + s * WS_STRIDE + NRB;
    const float meanv = __fdiv_rn(8192.0f, 72.0f);
    double sr = 0.0, si = 0.0;
    for (int j = part; j < NAB; j += 8) {
      float a = __fsub_rn((float)ah[j], meanv);
      double ang = -2.0 * M_PI * (double)(j * k) / 72.0;
      double sn, cs;
      sincos(ang, &sn, &cs);
      sr += (double)a * cs;
      si += (double)a * sn;
    }
    fr[sk][part] = sr; fi[sk][part] = si;
  }
  __syncthreads();
  if (t < 15) {
    double sr = 0.0, si = 0.0;
    for (int p = 0; p < 8; ++p) { sr += fr[t][p]; si += fi[t][p]; }
    descs[t / 5][20 + t % 5] = (float)sqrt(sr * sr + si * si);
  }
  if (t < 60) {
    descs[t / 20][t % 20] = __fdiv_rn((float)ws[(t / 20) * WS_STRIDE + (t % 20)], 8192.0f);
  }
  __syncthreads();
  if (t == 0) {
    double acc = 0.0;
    for (int j = 0; j < 26; ++j) {
      double a = descs[0][j], b = descs[1][j], c = descs[2][j];
      double m = (a + b + c) / 3.0;
      acc += ((a - m) * (a - m) + (b - m) * (b - m) + (c - m) * (c - m)) * 0.5;
    }
    out[0] = (float)(acc / 26.0);
  }
}

extern "C" void kernel_launch(void* const* d_in, const int* in_sizes, int n_in,
                              void* d_out, int out_size, void* d_ws, size_t ws_size,
                              hipStream_t stream) {
  const float* c0 = (const float*)d_in[0];
  const float* c1 = (const float*)d_in[1];
  const float* c2 = (const float*)d_in[2];
  int* ws = (int*)d_ws;
  float* out = (float*)d_out;
  hipLaunchKernelGGL(prep_kernel,  dim3(48),  dim3(256), 0, stream, c0, c1, c2, ws);
  hipLaunchKernelGGL(work_kernel,  dim3(816), dim3(256), 0, stream, c0, c1, c2, ws);
  hipLaunchKernelGGL(final_kernel, dim3(1),   dim3(256), 0, stream, ws, out);
}

// Round 5
// 41.140 us; speedup vs baseline: 5.4964x; 1.3776x over previous
//
#include <hip/hip_runtime.h>
#include <math.h>

#define NPTS 8192
#define NSEG 32            // j-segments per slide (256 pts each)
#define NRB 20
#define NAB 72
#define NHB 92             // NRB+NAB
// ws layout (int units):
#define HP_OFF 0           // hist partials: 12 blocks x 92 ints
#define CC_OFF 1280        // collision partial counts: 96 ints
#define DWS_OFF 2048       // float area: 32 seg-planes x 24576 rows

__device__ __forceinline__ const float* slide_ptr(const float* c0, const float* c1,
                                                  const float* c2, int s) {
  return s == 0 ? c0 : (s == 1 ? c1 : c2);
}

// 768 blocks = 3 slides x 8 rowblocks(1024 rows) x 32 segs(256 pts).
// Pure pair sweep: 4 rows/thread, dot-form distance, partial-min d2 STORED
// (no atomics, no init, replay/poison-safe).
__global__ __launch_bounds__(256) void sweep_kernel(const float* __restrict__ c0,
                                                    const float* __restrict__ c1,
                                                    const float* __restrict__ c2,
                                                    int* __restrict__ ws) {
  const int b = blockIdx.x;
  const int t = threadIdx.x;
  const int s   = b >> 8;
  const int rem = b & 255;
  const int rb  = rem >> 5;     // rowblock: 1024 rows
  const int seg = rem & 31;     // j-segment: 256 pts
  const float2* coords = (const float2*)slide_ptr(c0, c1, c2, s);
  const float4* c4 = (const float4*)coords;

  __shared__ float4 tile[128];  // 256 points
  if (t < 128) tile[t] = c4[seg * 128 + t];

  const int r0 = rb * 1024;
  float px[4], py[4], pp[4], dm[4];
  #pragma unroll
  for (int k = 0; k < 4; ++k) {
    float2 p = coords[r0 + t + k * 256];
    px[k] = p.x; py[k] = p.y;
    pp[k] = fmaf(p.y, p.y, p.x * p.x);
    dm[k] = INFINITY;           // min over (|q|^2/2 - p.q)
  }
  __syncthreads();

  if ((seg >> 2) == rb) {
    // tile contains the self-point of row (r0 + t + kd*256), kd = seg&3, at tile idx t
    const int kd = seg & 3;
    #pragma unroll 8
    for (int u = 0; u < 128; ++u) {
      float4 q = tile[u];
      float eq0 = 0.5f * fmaf(q.y, q.y, q.x * q.x);
      float eq1 = 0.5f * fmaf(q.w, q.w, q.z * q.z);
      #pragma unroll
      for (int k = 0; k < 4; ++k) {
        float v0 = fmaf(-py[k], q.y, fmaf(-px[k], q.x, eq0));
        float v1 = fmaf(-py[k], q.w, fmaf(-px[k], q.z, eq1));
        if (k == kd) {
          v0 = (2 * u == t)     ? INFINITY : v0;
          v1 = (2 * u + 1 == t) ? INFINITY : v1;
        }
        dm[k] = fminf(dm[k], fminf(v0, v1));
      }
    }
  } else {
    #pragma unroll 8
    for (int u = 0; u < 128; ++u) {
      float4 q = tile[u];
      float eq0 = 0.5f * fmaf(q.y, q.y, q.x * q.x);
      float eq1 = 0.5f * fmaf(q.w, q.w, q.z * q.z);
      #pragma unroll
      for (int k = 0; k < 4; ++k) {
        float v0 = fmaf(-py[k], q.y, fmaf(-px[k], q.x, eq0));
        float v1 = fmaf(-py[k], q.w, fmaf(-px[k], q.z, eq1));
        dm[k] = fminf(dm[k], fminf(v0, v1));
      }
    }
  }

  float* dws = (float*)(ws + DWS_OFF);
  const int srow = s * NPTS + r0 + t;   // global row
  #pragma unroll
  for (int k = 0; k < 4; ++k)
    dws[seg * 24576 + srow + k * 256] = fmaf(2.0f, dm[k], pp[k]);  // partial-min d2
}

// 108 blocks: 0..95 collision-count (256 rows each), 96..107 histogram units
// (3 slides x 4 parts of 2048 pts; each block self-computes center+rmax).
__global__ __launch_bounds__(256) void mid_kernel(const float* __restrict__ c0,
                                                  const float* __restrict__ c1,
                                                  const float* __restrict__ c2,
                                                  int* __restrict__ ws) {
  const int b = blockIdx.x;
  const int t = threadIdx.x;

  if (b < 96) {
    // ---- collision count: global rows [b*256, b*256+256) ----
    const float* dws = (const float*)(ws + DWS_OFF);
    const int row = b * 256 + t;
    float m = INFINITY;
    #pragma unroll 8
    for (int g = 0; g < NSEG; ++g) m = fminf(m, dws[g * 24576 + row]);
    __shared__ int red[256];
    red[t] = (m < 1e-4f) ? 1 : 0;   // d<0.01 <=> d2<1e-4
    __syncthreads();
    for (int o = 128; o > 0; o >>= 1) { if (t < o) red[t] += red[t + o]; __syncthreads(); }
    if (t == 0) ws[CC_OFF + b] = red[0];
    return;
  }

  // ---- histogram unit ----
  const int hb = b - 96;
  const int s = hb >> 2, part = hb & 3;
  const float4* c4 = (const float4*)slide_ptr(c0, c1, c2, s);

  __shared__ double redd[256];
  __shared__ float  redf[256];
  __shared__ float  cxs, cys, rmaxs;
  __shared__ int    h[NHB];

  // center: full-slide f64 sum (4096 float4 = 8192 pts; fixed order), rounded to f32
  double sx = 0.0, sy = 0.0;
  for (int j = 0; j < 16; ++j) {
    float4 v = c4[t + j * 256];
    sx += (double)v.x + (double)v.z;
    sy += (double)v.y + (double)v.w;
  }
  redd[t] = sx; __syncthreads();
  for (int o = 128; o > 0; o >>= 1) { if (t < o) redd[t] += redd[t + o]; __syncthreads(); }
  if (t == 0) cxs = (float)(redd[0] / (double)NPTS);
  __syncthreads();
  redd[t] = sy; __syncthreads();
  for (int o = 128; o > 0; o >>= 1) { if (t < o) redd[t] += redd[t + o]; __syncthreads(); }
  if (t == 0) cys = (float)(redd[0] / (double)NPTS);
  __syncthreads();
  const float cx = cxs, cy = cys;

  // rmax: full-slide scan (max is order-independent => deterministic)
  float rm = 0.0f;
  for (int j = 0; j < 16; ++j) {
    float4 v = c4[t + j * 256];
    float dx0 = __fsub_rn(v.x, cx), dy0 = __fsub_rn(v.y, cy);
    float dx1 = __fsub_rn(v.z, cx), dy1 = __fsub_rn(v.w, cy);
    float r0 = __fsqrt_rn(__fadd_rn(__fmul_rn(dx0, dx0), __fmul_rn(dy0, dy0)));
    float r1 = __fsqrt_rn(__fadd_rn(__fmul_rn(dx1, dx1), __fmul_rn(dy1, dy1)));
    rm = fmaxf(rm, fmaxf(r0, r1));
  }
  redf[t] = rm; __syncthreads();
  for (int o = 128; o > 0; o >>= 1) { if (t < o) redf[t] = fmaxf(redf[t], redf[t + o]); __syncthreads(); }
  if (t == 0) rmaxs = __fadd_rn(redf[0], 1e-8f);
  for (int i = t; i < NHB; i += 256) h[i] = 0;
  __syncthreads();
  const float rmaxp = rmaxs;

  // bin this block's 2048 points = 1024 float4 (exact f32 chains of the reference)
  for (int j = 0; j < 4; ++j) {
    float4 v = c4[part * 1024 + j * 256 + t];
    #pragma unroll
    for (int half = 0; half < 2; ++half) {
      float dx = __fsub_rn(half ? v.z : v.x, cx);
      float dy = __fsub_rn(half ? v.w : v.y, cy);
      float r  = __fsqrt_rn(__fadd_rn(__fmul_rn(dx, dx), __fmul_rn(dy, dy)));
      float rn = __fdiv_rn(r, rmaxp);
      int ri = (int)floorf(__fmul_rn(rn, 20.0f));
      ri = min(max(ri, 0), NRB - 1);
      atomicAdd(&h[ri], 1);
      float ang = (float)atan2((double)dy, (double)dx);  // correctly-rounded f32 atan2
      float tt = __fadd_rn(ang, 3.14159274101257324f);   // + float(pi)
      float uu = __fdiv_rn(tt, 6.28318548202514648f);    // / float(2*pi)
      float vv = __fmul_rn(uu, 72.0f);
      int ai = (int)floorf(vv);
      ai = min(max(ai, 0), NAB - 1);
      atomicAdd(&h[NRB + ai], 1);
    }
  }
  __syncthreads();
  if (t < NHB) ws[HP_OFF + hb * NHB + t] = h[t];   // partial hist, distinct slot
}

// One block: sum hist partials, DFT magnitudes, collision sums, variance.
__global__ __launch_bounds__(256) void final_kernel(const int* __restrict__ ws,
                                                    float* __restrict__ out) {
  __shared__ int ah[3][NHB];
  __shared__ double fr[15][8], fi[15][8];
  __shared__ float descs[3][26];
  const int t = threadIdx.x;

  for (int i = t; i < 3 * NHB; i += 256) {
    int s = i / NHB, bin = i % NHB;
    int v = 0;
    #pragma unroll
    for (int p = 0; p < 4; ++p) v += ws[HP_OFF + (s * 4 + p) * NHB + bin];
    ah[s][bin] = v;
  }
  __syncthreads();

  if (t < 120) {
    const int part = t & 7;
    const int sk = t >> 3;        // slide*5 + k
    const int s = sk / 5;
    const int k = sk % 5;
    const float meanv = __fdiv_rn(8192.0f, 72.0f);
    double sr = 0.0, si = 0.0;
    for (int j = part; j < NAB; j += 8) {
      float a = __fsub_rn((float)ah[s][NRB + j], meanv);
      double ang = -2.0 * M_PI * (double)(j * k) / 72.0;
      double sn, cs;
      sincos(ang, &sn, &cs);
      sr += (double)a * cs;
      si += (double)a * sn;
    }
    fr[sk][part] = sr; fi[sk][part] = si;
  }
  if (t >= 120 && t < 123) {
    int s = t - 120;
    int c = 0;
    for (int i = 0; i < 32; ++i) c += ws[CC_OFF + s * 32 + i];
    descs[s][25] = __fdiv_rn((float)c, 8192.0f);
  }
  if (t >= 128 && t < 188) {
    int i = t - 128;
    descs[i / 20][i % 20] = __fdiv_rn((float)ah[i / 20][i % 20], 8192.0f);
  }
  __syncthreads();
  if (t < 15) {
    double sr = 0.0, si = 0.0;
    #pragma unroll
    for (int p = 0; p < 8; ++p) { sr += fr[t][p]; si += fi[t][p]; }
    descs[t / 5][20 + t % 5] = (float)sqrt(sr * sr + si * si);
  }
  __syncthreads();
  if (t == 0) {
    double acc = 0.0;
    for (int j = 0; j < 26; ++j) {
      double a = descs[0][j], b = descs[1][j], c = descs[2][j];
      double m = (a + b + c) / 3.0;
      acc += ((a - m) * (a - m) + (b - m) * (b - m) + (c - m) * (c - m)) * 0.5;
    }
    out[0] = (float)(acc / 26.0);
  }
}

extern "C" void kernel_launch(void* const* d_in, const int* in_sizes, int n_in,
                              void* d_out, int out_size, void* d_ws, size_t ws_size,
                              hipStream_t stream) {
  const float* c0 = (const float*)d_in[0];
  const float* c1 = (const float*)d_in[1];
  const float* c2 = (const float*)d_in[2];
  int* ws = (int*)d_ws;
  float* out = (float*)d_out;
  hipLaunchKernelGGL(sweep_kernel, dim3(768), dim3(256), 0, stream, c0, c1, c2, ws);
  hipLaunchKernelGGL(mid_kernel,   dim3(108), dim3(256), 0, stream, c0, c1, c2, ws);
  hipLaunchKernelGGL(final_kernel, dim3(1),   dim3(256), 0, stream, ws, out);
}